// Round 1
// baseline (243.243 us; speedup 1.0000x reference)
//
#include <hip/hip_runtime.h>

// out[b] = x[b,:]·u + C, where
//   v[g] = sum_h W2[h]*W1[h,g]
//   u[s] = sum_{e: snp_idx[e]==s} edge_w[e]*v[gene_idx[e]]
//   C    = gene_bias·v + W2·b1 + b2
// Valid because the reference network is entirely linear (no activation).

__global__ void compute_v_kernel(const float* __restrict__ W1,
                                 const float* __restrict__ W2,
                                 const float* __restrict__ b1,
                                 const float* __restrict__ b2,
                                 const float* __restrict__ gene_bias,
                                 float* __restrict__ v,
                                 float* __restrict__ Cptr,
                                 int G, int H)
{
    __shared__ float red[256];
    const int tid = threadIdx.x;
    const int gl  = tid & 63;      // gene lane within tile
    const int hg  = tid >> 6;      // h-group 0..3 (wave-uniform)
    const int g   = blockIdx.x * 64 + gl;

    float acc = 0.f;
    if (g < G) {
        for (int h = hg; h < H; h += 4) {
            acc += W2[h] * W1[(size_t)h * G + g];   // coalesced over g, W2 wave-uniform
        }
    }
    red[tid] = acc;
    __syncthreads();

    float cc = 0.f;
    if (hg == 0 && g < G) {
        float vg = red[gl] + red[64 + gl] + red[128 + gl] + red[192 + gl];
        v[g] = vg;
        cc = gene_bias[g] * vg;
    }
    if (blockIdx.x == 0) {
        for (int h = tid; h < H; h += blockDim.x) cc += W2[h] * b1[h];
        if (tid == 0) cc += b2[0];
    }
    __syncthreads();
    red[tid] = cc;
    __syncthreads();
    for (int s = 128; s > 0; s >>= 1) {
        if (tid < s) red[tid] += red[tid + s];
        __syncthreads();
    }
    if (tid == 0) atomicAdd(Cptr, red[0]);
}

__global__ void scatter_u_kernel(const int* __restrict__ snp_idx,
                                 const int* __restrict__ gene_idx,
                                 const float* __restrict__ edge_w,
                                 const float* __restrict__ v,
                                 float* __restrict__ u,
                                 int E)
{
    int i = blockIdx.x * blockDim.x + threadIdx.x;
    if (i < E) {
        atomicAdd(&u[snp_idx[i]], edge_w[i] * v[gene_idx[i]]);
    }
}

__global__ __launch_bounds__(1024)
void output_kernel(const float* __restrict__ x,
                   const float* __restrict__ u,
                   const float* __restrict__ Cptr,
                   float* __restrict__ out,
                   int S)
{
    const int b   = blockIdx.x;
    const int tid = threadIdx.x;
    const float* xr = x + (size_t)b * S;
    float acc = 0.f;

    if ((S & 3) == 0) {
        const float4* x4 = (const float4*)xr;   // row offset b*S*4 is 16B-aligned when S%4==0
        const float4* u4 = (const float4*)u;
        const int S4 = S >> 2;
        for (int i = tid; i < S4; i += (int)blockDim.x) {
            float4 a = x4[i];
            float4 c = u4[i];
            acc += a.x * c.x + a.y * c.y + a.z * c.z + a.w * c.w;
        }
    } else {
        for (int i = tid; i < S; i += (int)blockDim.x) acc += xr[i] * u[i];
    }

    // wave (64-lane) shuffle reduce, then cross-wave via LDS
    for (int off = 32; off > 0; off >>= 1) acc += __shfl_down(acc, off, 64);
    __shared__ float wsum[16];
    const int wave = tid >> 6;
    const int lane = tid & 63;
    if (lane == 0) wsum[wave] = acc;
    __syncthreads();
    if (tid == 0) {
        float t = 0.f;
        const int nwaves = (int)blockDim.x >> 6;
        for (int w = 0; w < nwaves; ++w) t += wsum[w];
        out[b] = t + Cptr[0];
    }
}

extern "C" void kernel_launch(void* const* d_in, const int* in_sizes, int n_in,
                              void* d_out, int out_size, void* d_ws, size_t ws_size,
                              hipStream_t stream)
{
    const float* x         = (const float*)d_in[0];
    const int*   snp_idx   = (const int*)  d_in[1];
    const int*   gene_idx  = (const int*)  d_in[2];
    const float* edge_w    = (const float*)d_in[3];
    const float* gene_bias = (const float*)d_in[4];
    const float* W1        = (const float*)d_in[5];
    const float* b1        = (const float*)d_in[6];
    const float* W2        = (const float*)d_in[7];
    const float* b2        = (const float*)d_in[8];
    float* out = (float*)d_out;

    const int B = out_size;            // 256
    const int E = in_sizes[1];         // 600000
    const int G = in_sizes[4];         // 18000
    const int H = in_sizes[6];         // 256
    const int S = in_sizes[0] / B;     // 100000

    // Workspace layout: u[S] | v[G] | C[1]
    float* u    = (float*)d_ws;
    float* v    = u + S;
    float* Cptr = v + G;

    // Zero u, v, C (ws is re-poisoned to 0xAA before every timed launch).
    hipMemsetAsync(d_ws, 0, (size_t)(S + G + 1) * sizeof(float), stream);

    const int nbv = (G + 63) / 64;
    compute_v_kernel<<<nbv, 256, 0, stream>>>(W1, W2, b1, b2, gene_bias, v, Cptr, G, H);

    const int nbs = (E + 255) / 256;
    scatter_u_kernel<<<nbs, 256, 0, stream>>>(snp_idx, gene_idx, edge_w, v, u, E);

    output_kernel<<<B, 1024, 0, stream>>>(x, u, Cptr, out, S);
}

// Round 2
// 241.219 us; speedup vs baseline: 1.0084x; 1.0084x over previous
//
#include <hip/hip_runtime.h>

// Linear collapse of the whole network (no activation anywhere in the ref):
//   out[b] = x[b,:]·u + C
//   v[g]   = sum_h W2[h]*W1[h,g]
//   u[s]   = sum_{e: snp_idx[e]==s} edge_w[e]*v[gene_idx[e]]
//   C      = gene_bias·v + W2·b1 + b2
//
// Kernel 1: zero u (grid-stride float4), compute v, write per-block C-partials
//           (race-free: every block writes its own Cpart slot, no init needed).
// Kernel 2: edge scatter into u (atomicAdd, 4 edges/thread vector loads).
// Kernel 3: B-row GEMV x·u; Cpart summed by seeding acc for tid<nC.

__global__ void compute_v_kernel(const float* __restrict__ W1,
                                 const float* __restrict__ W2,
                                 const float* __restrict__ b1,
                                 const float* __restrict__ b2,
                                 const float* __restrict__ gene_bias,
                                 float* __restrict__ v,
                                 float* __restrict__ Cpart,
                                 float4* __restrict__ u4,
                                 int G, int H, int nU4)
{
    __shared__ float red[256];
    const int tid = threadIdx.x;

    // Zero-init u (covers any float4 padding too). No dependency with v work.
    {
        const int gid = blockIdx.x * 256 + tid;
        const int tot = gridDim.x * 256;
        const float4 z = make_float4(0.f, 0.f, 0.f, 0.f);
        for (int i = gid; i < nU4; i += tot) u4[i] = z;
    }

    const int gl = tid & 63;      // gene lane within 64-wide tile
    const int hg = tid >> 6;      // wave index = h-group 0..3 (wave-uniform)
    const int g  = blockIdx.x * 64 + gl;

    float acc = 0.f;
    if (g < G) {
        for (int h = hg; h < H; h += 4) {
            acc += W2[h] * W1[(size_t)h * G + g];   // W2 scalar load, W1 coalesced
        }
    }
    red[tid] = acc;
    __syncthreads();

    float cc = 0.f;
    if (hg == 0 && g < G) {
        float vg = red[gl] + red[64 + gl] + red[128 + gl] + red[192 + gl];
        v[g] = vg;
        cc = gene_bias[g] * vg;
    }
    if (blockIdx.x == 0) {
        for (int h = tid; h < H; h += 256) cc += W2[h] * b1[h];
        if (tid == 0) cc += b2[0];
    }
    __syncthreads();
    red[tid] = cc;
    __syncthreads();
    for (int s = 128; s > 0; s >>= 1) {
        if (tid < s) red[tid] += red[tid + s];
        __syncthreads();
    }
    if (tid == 0) Cpart[blockIdx.x] = red[0];   // every block writes: no init, no atomics
}

__global__ void scatter_u_kernel(const int* __restrict__ snp_idx,
                                 const int* __restrict__ gene_idx,
                                 const float* __restrict__ edge_w,
                                 const float* __restrict__ v,
                                 float* __restrict__ u,
                                 int E)
{
    const int i4 = blockIdx.x * blockDim.x + threadIdx.x;
    const int base = i4 * 4;
    if (base + 3 < E) {
        const int4   s = *(const int4*)  (snp_idx  + base);
        const int4   g = *(const int4*)  (gene_idx + base);
        const float4 w = *(const float4*)(edge_w   + base);
        atomicAdd(&u[s.x], w.x * v[g.x]);
        atomicAdd(&u[s.y], w.y * v[g.y]);
        atomicAdd(&u[s.z], w.z * v[g.z]);
        atomicAdd(&u[s.w], w.w * v[g.w]);
    } else {
        for (int i = base; i < E; ++i)
            atomicAdd(&u[snp_idx[i]], edge_w[i] * v[gene_idx[i]]);
    }
}

__global__ __launch_bounds__(1024)
void output_kernel(const float* __restrict__ x,
                   const float* __restrict__ u,
                   const float* __restrict__ Cpart,
                   int nC,
                   float* __restrict__ out,
                   int S)
{
    const int b   = blockIdx.x;
    const int tid = threadIdx.x;
    float acc = (tid < nC) ? Cpart[tid] : 0.f;   // fold constant term into reduction

    const float* xr = x + (size_t)b * S;
    const int S4 = S >> 2;
    const float4* x4 = (const float4*)xr;        // b*S*4 is 16B-aligned when S%4==0
    const float4* u4 = (const float4*)u;
    for (int i = tid; i < S4; i += 1024) {
        float4 a = x4[i];
        float4 c = u4[i];
        acc += a.x * c.x + a.y * c.y + a.z * c.z + a.w * c.w;
    }
    for (int i = (S4 << 2) + tid; i < S; i += 1024) acc += xr[i] * u[i];

    for (int off = 32; off > 0; off >>= 1) acc += __shfl_down(acc, off, 64);
    __shared__ float wsum[16];
    const int wave = tid >> 6;
    const int lane = tid & 63;
    if (lane == 0) wsum[wave] = acc;
    __syncthreads();
    if (tid == 0) {
        float t = 0.f;
        for (int w = 0; w < 16; ++w) t += wsum[w];
        out[b] = t;
    }
}

extern "C" void kernel_launch(void* const* d_in, const int* in_sizes, int n_in,
                              void* d_out, int out_size, void* d_ws, size_t ws_size,
                              hipStream_t stream)
{
    const float* x         = (const float*)d_in[0];
    const int*   snp_idx   = (const int*)  d_in[1];
    const int*   gene_idx  = (const int*)  d_in[2];
    const float* edge_w    = (const float*)d_in[3];
    const float* gene_bias = (const float*)d_in[4];
    const float* W1        = (const float*)d_in[5];
    const float* b1        = (const float*)d_in[6];
    const float* W2        = (const float*)d_in[7];
    const float* b2        = (const float*)d_in[8];
    float* out = (float*)d_out;

    const int B = out_size;            // 256
    const int E = in_sizes[1];         // 600000
    const int G = in_sizes[4];         // 18000
    const int H = in_sizes[6];         // 256
    const int S = in_sizes[0] / B;     // 100000

    // Workspace layout: u[nU4*4] | v[G] | Cpart[nbv]
    const int nU4 = (S + 3) / 4;
    float* u     = (float*)d_ws;
    float* v     = u + (size_t)nU4 * 4;
    const int nbv = (G + 63) / 64;     // 282 (must stay <= 1024 for Cpart fold)
    float* Cpart = v + G;

    compute_v_kernel<<<nbv, 256, 0, stream>>>(W1, W2, b1, b2, gene_bias,
                                              v, Cpart, (float4*)u, G, H, nU4);

    const int nE4 = (E + 3) / 4;
    scatter_u_kernel<<<(nE4 + 255) / 256, 256, 0, stream>>>(snp_idx, gene_idx, edge_w,
                                                            v, u, E);

    output_kernel<<<B, 1024, 0, stream>>>(x, u, Cpart, nbv, out, S);
}